// Round 2
// baseline (815.056 us; speedup 1.0000x reference)
//
#include <hip/hip_runtime.h>
#include <math.h>

// Problem constants (match reference file)
#define BATCH 8192
#define NFEAT 256
#define H1 100
#define H2 50
#define FPB 8    // features handled sequentially per thread

// Grid: x = BATCH/256 batch chunks, y = NFEAT/FPB feature groups.
// One thread = one batch row, looping over FPB features.
//
// Loop order h-outer / o-inner so the ONLY live per-thread state is the
// 50-element fc2 accumulator (fully unrolled -> VGPRs). Round-1 version kept
// h1[100] live across the o-loop and spilled to scratch (VGPR_Count=56,
// VALUBusy 39%). Weight indices are wave-uniform (blockIdx + loop constants)
// -> s_load via scalar cache; vector pipe runs the 50 independent FMA chains.
__global__ __launch_bounds__(256) void nam_main(
    const float* __restrict__ x,
    const float* __restrict__ W1,
    const float* __restrict__ b1,
    const float* __restrict__ W2,
    const float* __restrict__ b2,
    const float* __restrict__ W3,
    float* __restrict__ acc_out)
{
    const int b  = blockIdx.x * blockDim.x + threadIdx.x; // batch row
    const int f0 = blockIdx.y * FPB;

    float contrib = 0.0f;

#pragma unroll 1
    for (int j = 0; j < FPB; ++j) {
        const int f = f0 + j;
        const float xv = x[b * NFEAT + f];

        const float* __restrict__ w1p = W1 + f * H1;
        const float* __restrict__ b1p = b1 + f * H1;
        const float* __restrict__ w2p = W2 + (size_t)f * H2 * H1;
        const float* __restrict__ b2p = b2 + f * H2;
        const float* __restrict__ w3p = W3 + f * H2;

        float acc[H2];
#pragma unroll
        for (int o = 0; o < H2; ++o) acc[o] = b2p[o];

        // h outer (rolled, step 2 -> contiguous dwordx2 weight loads),
        // o inner (fully unrolled -> acc[] stays in registers).
#pragma unroll 1
        for (int h = 0; h < H1; h += 2) {
            const float h1a = fmaxf(0.0f, fmaf(xv, w1p[h],     b1p[h]));
            const float h1b = fmaxf(0.0f, fmaf(xv, w1p[h + 1], b1p[h + 1]));
#pragma unroll
            for (int o = 0; o < H2; ++o) {
                const float* __restrict__ w = w2p + o * H1 + h;
                acc[o] = fmaf(h1a, w[0], acc[o]);
                acc[o] = fmaf(h1b, w[1], acc[o]);
            }
        }

        // fc3: relu(acc) dot W3[f]
#pragma unroll
        for (int o = 0; o < H2; ++o) {
            contrib = fmaf(fmaxf(0.0f, acc[o]), w3p[o], contrib);
        }
    }

    // Per-thread partial over FPB features -> device-scope atomic into d_out.
    atomicAdd(&acc_out[b], contrib);
}

__global__ __launch_bounds__(256) void nam_finish(
    float* __restrict__ out, const float* __restrict__ bias)
{
    const int b = blockIdx.x * blockDim.x + threadIdx.x;
    const float v = out[b] + bias[0];
    out[b] = 1.0f / (1.0f + expf(-v));
}

extern "C" void kernel_launch(void* const* d_in, const int* in_sizes, int n_in,
                              void* d_out, int out_size, void* d_ws, size_t ws_size,
                              hipStream_t stream) {
    const float* x    = (const float*)d_in[0];
    const float* W1   = (const float*)d_in[1];
    const float* b1   = (const float*)d_in[2];
    const float* W2   = (const float*)d_in[3];
    const float* b2   = (const float*)d_in[4];
    const float* W3   = (const float*)d_in[5];
    const float* bias = (const float*)d_in[6];
    float* out = (float*)d_out;

    // d_out is poisoned 0xAA before every timed replay -> zero it ourselves.
    hipMemsetAsync(out, 0, (size_t)BATCH * sizeof(float), stream);

    dim3 grid(BATCH / 256, NFEAT / FPB);
    nam_main<<<grid, 256, 0, stream>>>(x, W1, b1, W2, b2, W3, out);

    nam_finish<<<BATCH / 256, 256, 0, stream>>>(out, bias);
}

// Round 3
// 239.206 us; speedup vs baseline: 3.4073x; 3.4073x over previous
//
#include <hip/hip_runtime.h>
#include <math.h>

// Problem constants
#define BATCH 8192
#define NFEAT 256
#define NH1   100     // fc1 width (K of fc2)
#define NH2   50      // fc2 width (N of fc2)
#define KP    128     // K padded to 4 MFMA k-steps of 32
#define KL    136     // LDS row stride in bf16 elems (+8 -> 2-way bank aliasing = free)
#define NP    64      // N padded to 4 tiles of 16
#define MBLK  128     // batch rows per block

typedef __attribute__((ext_vector_type(8))) short short8;   // 8 bf16 (4 VGPRs)
typedef __attribute__((ext_vector_type(4))) float float4v;  // MFMA acc

__device__ __forceinline__ unsigned bf16_rne(float x) {
    unsigned u = __float_as_uint(x);
    return (u + 0x7fffu + ((u >> 16) & 1u)) >> 16;
}
__device__ __forceinline__ unsigned pack_bf16x2(float a, float b) {
    return bf16_rne(a) | (bf16_rne(b) << 16);
}

// x [B][F] -> xT [F][B], 64x64 LDS tiles, fully coalesced both sides.
__global__ __launch_bounds__(256) void transpose_x(
    const float* __restrict__ x, float* __restrict__ xT)
{
    __shared__ float tile[64][65];
    const int t  = threadIdx.x;
    const int b0 = blockIdx.x * 64;
    const int f0 = blockIdx.y * 64;
    const int c  = t & 63, r0 = t >> 6;
#pragma unroll
    for (int i = 0; i < 16; ++i) {
        const int r = r0 + i * 4;
        tile[r][c] = x[(size_t)(b0 + r) * NFEAT + f0 + c];
    }
    __syncthreads();
#pragma unroll
    for (int i = 0; i < 16; ++i) {
        const int r = r0 + i * 4;   // feature offset within tile
        xT[(size_t)(f0 + r) * BATCH + b0 + c] = tile[c][r];
    }
}

// One block = (128 batch rows, one feature). fc1 on VALU -> LDS bf16;
// fc2 via mfma_f32_16x16x32_bf16; fc3 + n-reduction in epilogue.
__global__ __launch_bounds__(256, 2) void nam_mfma(
    const float* __restrict__ xT,
    const float* __restrict__ W1,
    const float* __restrict__ b1,
    const float* __restrict__ W2,
    const float* __restrict__ b2,
    const float* __restrict__ W3,
    float* __restrict__ out)
{
    __shared__ __align__(16) unsigned short h1s[MBLK * KL];  // A: [m][k] bf16
    __shared__ __align__(16) unsigned short w2s[NP * KL];    // B^T rows: [n][k] bf16
    __shared__ float b2s[NP];
    __shared__ float w3s[NP];

    const int t  = threadIdx.x;
    const int b0 = blockIdx.x * MBLK;
    const int f  = blockIdx.y;

    // ---- phase A: zero pads (disjoint from real-data region of h1s) ----
    {   // w2s fully zeroed (real fill overlaps -> barrier below)
        const int4 z = make_int4(0, 0, 0, 0);
#pragma unroll
        for (int i = 0; i < 5; ++i) {
            const int idx = i * 256 + t;
            if (idx < (NP * KL * 2) / 16) ((int4*)w2s)[idx] = z;
        }
        // h1s pad cols 100..135 (u32 cols 50..67)
        const int row = t & 127, half = t >> 7;
#pragma unroll
        for (int i = 0; i < 9; ++i)
            ((unsigned*)h1s)[row * (KL / 2) + 50 + half * 9 + i] = 0u;
    }
    __syncthreads();

    // ---- phase B: fc1 into h1s; W2 cvt into w2s; b2/w3 into LDS ----
    {
        const int row = t & 127, half = t >> 7;
        const float xv = xT[(size_t)f * BATCH + b0 + row];
        const float* __restrict__ w1p = W1 + f * NH1;
        const float* __restrict__ b1p = b1 + f * NH1;
#pragma unroll
        for (int i = 0; i < 25; ++i) {
            const int hp = half * 25 + i;      // h pair 0..49
            const int h  = hp * 2;
            const float2 w  = *(const float2*)(w1p + h);
            const float2 bb = *(const float2*)(b1p + h);
            const float v0 = fmaxf(0.f, fmaf(xv, w.x, bb.x));
            const float v1 = fmaxf(0.f, fmaf(xv, w.y, bb.y));
            ((unsigned*)h1s)[row * (KL / 2) + hp] = pack_bf16x2(v0, v1);
        }
        const float* __restrict__ w2g = W2 + (size_t)f * NH2 * NH1;
#pragma unroll
        for (int i = 0; i < 10; ++i) {
            const int idx = i * 256 + t;       // (o, h-pair) pairs: 50*50
            if (idx < NH2 * 50) {
                const int o  = idx / 50;
                const int hp = idx - o * 50;
                const float2 w = *(const float2*)(w2g + o * NH1 + hp * 2);
                ((unsigned*)w2s)[o * (KL / 2) + hp] = pack_bf16x2(w.x, w.y);
            }
        }
        if (t < NP)            b2s[t]      = (t < NH2)      ? b2[f * NH2 + t] : 0.f;
        else if (t < 2 * NP)   w3s[t - NP] = (t - NP < NH2) ? W3[f * NH2 + (t - NP)] : 0.f;
    }
    __syncthreads();

    // ---- phase C: MFMA K-loop ----
    const int ln = t & 15;          // col within tile
    const int qd = (t >> 4) & 3;    // k-quad / row-quad
    const int wv = t >> 6;          // wave 0..3
    const int mt0 = wv * 2;         // this wave's 2 M-tiles

    float4v acc[2][4];
#pragma unroll
    for (int m2 = 0; m2 < 2; ++m2)
#pragma unroll
        for (int nt = 0; nt < 4; ++nt) acc[m2][nt] = (float4v){0.f, 0.f, 0.f, 0.f};

    const unsigned abase0 = (unsigned)(mt0 * 16 + ln) * KL;
    const unsigned abase1 = abase0 + 16 * KL;
    const unsigned bbase  = (unsigned)ln * KL;

#pragma unroll
    for (int kk = 0; kk < 4; ++kk) {
        const int ko = kk * 32 + qd * 8;
        const short8 a0 = *(const short8*)(h1s + abase0 + ko);
        const short8 a1 = *(const short8*)(h1s + abase1 + ko);
        short8 bf[4];
#pragma unroll
        for (int nt = 0; nt < 4; ++nt)
            bf[nt] = *(const short8*)(w2s + bbase + nt * 16 * KL + ko);
#pragma unroll
        for (int nt = 0; nt < 4; ++nt) {
            acc[0][nt] = __builtin_amdgcn_mfma_f32_16x16x32_bf16(a0, bf[nt], acc[0][nt], 0, 0, 0);
            acc[1][nt] = __builtin_amdgcn_mfma_f32_16x16x32_bf16(a1, bf[nt], acc[1][nt], 0, 0, 0);
        }
    }

    // ---- epilogue: h2 = relu(acc + b2); contribution = h2 . w3; reduce cols ----
    float rp[2][4] = {{0.f, 0.f, 0.f, 0.f}, {0.f, 0.f, 0.f, 0.f}};
#pragma unroll
    for (int nt = 0; nt < 4; ++nt) {
        const int o = nt * 16 + ln;
        const float bo = b2s[o], wo = w3s[o];
#pragma unroll
        for (int m2 = 0; m2 < 2; ++m2)
#pragma unroll
            for (int r = 0; r < 4; ++r) {
                const float v = fmaxf(acc[m2][nt][r] + bo, 0.f);
                rp[m2][r] = fmaf(v, wo, rp[m2][r]);
            }
    }
#pragma unroll
    for (int m2 = 0; m2 < 2; ++m2)
#pragma unroll
        for (int r = 0; r < 4; ++r) {
            float v = rp[m2][r];
            v += __shfl_xor(v, 1);
            v += __shfl_xor(v, 2);
            v += __shfl_xor(v, 4);
            v += __shfl_xor(v, 8);
            if (ln == 0)
                atomicAdd(out + b0 + (mt0 + m2) * 16 + qd * 4 + r, v);
        }
}

__global__ __launch_bounds__(256) void nam_finish(
    float* __restrict__ out, const float* __restrict__ bias)
{
    const int b = blockIdx.x * blockDim.x + threadIdx.x;
    const float v = out[b] + bias[0];
    out[b] = 1.0f / (1.0f + expf(-v));
}

extern "C" void kernel_launch(void* const* d_in, const int* in_sizes, int n_in,
                              void* d_out, int out_size, void* d_ws, size_t ws_size,
                              hipStream_t stream) {
    const float* x    = (const float*)d_in[0];
    const float* W1   = (const float*)d_in[1];
    const float* b1   = (const float*)d_in[2];
    const float* W2   = (const float*)d_in[3];
    const float* b2   = (const float*)d_in[4];
    const float* W3   = (const float*)d_in[5];
    const float* bias = (const float*)d_in[6];
    float* out = (float*)d_out;
    float* xT  = (float*)d_ws;   // NFEAT*BATCH floats = 8 MB

    // out accumulated via atomics -> zero first (harness poisons 0xAA)
    hipMemsetAsync(out, 0, (size_t)BATCH * sizeof(float), stream);

    transpose_x<<<dim3(BATCH / 64, NFEAT / 64), 256, 0, stream>>>(x, xT);

    nam_mfma<<<dim3(BATCH / MBLK, NFEAT), 256, 0, stream>>>(
        xT, W1, b1, W2, b2, W3, out);

    nam_finish<<<BATCH / 256, 256, 0, stream>>>(out, bias);
}

// Round 4
// 165.875 us; speedup vs baseline: 4.9137x; 1.4421x over previous
//
#include <hip/hip_runtime.h>
#include <math.h>

// Problem constants
#define BATCH 8192
#define NFEAT 256
#define NH1   100     // fc1 width (K of fc2)
#define NH2   50      // fc2 width (N of fc2)
#define KP    128     // K padded: 4 MFMA k-steps of 32
#define NP    64      // N padded: 4 n-tiles of 16

typedef __attribute__((ext_vector_type(8))) short short8;   // 8 bf16 (4 VGPRs)
typedef __attribute__((ext_vector_type(4))) float float4v;  // MFMA acc

// ---- workspace layout (floats/halves, all rebuilt every call) ----
// w2b   : NFEAT*4*4*64*8 bf16  = 4 MB   (fragment-ordered, zero-padded)
// w1p   : NFEAT*KP fp32        = 128 KB (zero-padded)
// b1p   : NFEAT*KP fp32        = 128 KB
// b2p   : NFEAT*NP fp32        = 64 KB  (zero-padded)
// w3p   : NFEAT*NP fp32        = 64 KB
// xT    : NFEAT*BATCH fp32     = 8 MB
#define W2B_ELEMS  (NFEAT * 4 * 4 * 64 * 8)
#define OFF_W1P    (W2B_ELEMS / 2)            // in fp32 units from ws start
#define OFF_B1P    (OFF_W1P + NFEAT * KP)
#define OFF_B2P    (OFF_B1P + NFEAT * KP)
#define OFF_W3P    (OFF_B2P + NFEAT * NP)
#define OFF_XT     (OFF_W3P + NFEAT * NP)

__device__ __forceinline__ unsigned bf16_rne(float x) {
    unsigned u = __float_as_uint(x);
    return (u + 0x7fffu + ((u >> 16) & 1u)) >> 16;
}
// round-half-up pack of two floats -> bf16x2 (2 adds + v_perm pattern).
// Ties (low16==0x8000) round away instead of to-even: negligible for data.
__device__ __forceinline__ unsigned pack_bf16_rhu(float a, float b) {
    unsigned ua = __float_as_uint(a) + 0x8000u;
    unsigned ub = __float_as_uint(b) + 0x8000u;
    return (ua >> 16) | (ub & 0xFFFF0000u);
}

// ---- pre-pass: pad + convert weights; w2b in exact B-fragment order ----
// w2b[f][kk][nt][lane][j] = bf16(W2[f][o=16*nt+(lane&15)][h=32*kk+8*(lane>>4)+j])
__global__ __launch_bounds__(256) void prep_weights(
    const float* __restrict__ W1, const float* __restrict__ b1,
    const float* __restrict__ W2, const float* __restrict__ b2,
    const float* __restrict__ W3, float* __restrict__ ws)
{
    const int f = blockIdx.x;
    const int t = threadIdx.x;
    float* w1p = ws + OFF_W1P + f * KP;
    float* b1p = ws + OFF_B1P + f * KP;
    float* b2p = ws + OFF_B2P + f * NP;
    float* w3p = ws + OFF_W3P + f * NP;
    unsigned short* w2b = (unsigned short*)ws + (size_t)f * (4 * 4 * 64 * 8);

    if (t < KP) {
        w1p[t] = (t < NH1) ? W1[f * NH1 + t] : 0.f;
        b1p[t] = (t < NH1) ? b1[f * NH1 + t] : 0.f;
    }
    if (t < NP)               b2p[t]      = (t < NH2)      ? b2[f * NH2 + t] : 0.f;
    else if (t < 2 * NP)      w3p[t - NP] = (t - NP < NH2) ? W3[f * NH2 + (t - NP)] : 0.f;

    const float* w2g = W2 + (size_t)f * NH2 * NH1;
#pragma unroll
    for (int i = 0; i < 32; ++i) {
        const int e    = i * 256 + t;        // 0..8191
        const int j    = e & 7;
        const int lane = (e >> 3) & 63;
        const int nt   = (e >> 9) & 3;
        const int kk   = e >> 11;
        const int o    = nt * 16 + (lane & 15);
        const int h    = kk * 32 + (lane >> 4) * 8 + j;
        const float v  = (o < NH2 && h < NH1) ? w2g[o * NH1 + h] : 0.f;
        w2b[e] = (unsigned short)bf16_rne(v);
    }
}

// x [B][F] -> xT [F][B]
__global__ __launch_bounds__(256) void transpose_x(
    const float* __restrict__ x, float* __restrict__ xT)
{
    __shared__ float tile[64][65];
    const int t  = threadIdx.x;
    const int b0 = blockIdx.x * 64;
    const int f0 = blockIdx.y * 64;
    const int c  = t & 63, r0 = t >> 6;
#pragma unroll
    for (int i = 0; i < 16; ++i)
        tile[r0 + i * 4][c] = x[(size_t)(b0 + r0 + i * 4) * NFEAT + f0 + c];
    __syncthreads();
#pragma unroll
    for (int i = 0; i < 16; ++i)
        xT[(size_t)(f0 + r0 + i * 4) * BATCH + b0 + c] = tile[c][r0 + i * 4];
}

// ---- main: one wave = (32 batch rows, one feature). No LDS, no barriers.
// fc1 computed directly into A-fragment registers; B-fragments streamed
// from fragment-ordered w2b (coalesced 1KB/load, L1-hot across blocks).
__global__ __launch_bounds__(256, 2) void nam_mfma(
    const float* __restrict__ ws,
    float* __restrict__ out)
{
    const int t  = threadIdx.x;
    const int wv = t >> 6;
    const int ln = t & 15;
    const int qd = (t >> 4) & 3;
    const int f  = blockIdx.y * 4 + wv;
    const int b0 = blockIdx.x * 32;

    const float* xTp = ws + OFF_XT + (size_t)f * BATCH + b0;
    const float* w1p = ws + OFF_W1P + f * KP;
    const float* b1p = ws + OFF_B1P + f * KP;
    const unsigned short* w2b =
        (const unsigned short*)ws + (size_t)f * (4 * 4 * 64 * 8) + (t & 63) * 8;

    const float xv0 = xTp[ln];        // row = b0 + ln        (mt=0)
    const float xv1 = xTp[16 + ln];   // row = b0 + 16 + ln   (mt=1)

    float4v acc[2][4];
#pragma unroll
    for (int mt = 0; mt < 2; ++mt)
#pragma unroll
        for (int nt = 0; nt < 4; ++nt) acc[mt][nt] = (float4v){0.f, 0.f, 0.f, 0.f};

#pragma unroll
    for (int kk = 0; kk < 4; ++kk) {
        const int kbase = kk * 32 + qd * 8;
        const float4 w0 = *(const float4*)(w1p + kbase);
        const float4 w1 = *(const float4*)(w1p + kbase + 4);
        const float4 c0 = *(const float4*)(b1p + kbase);
        const float4 c1 = *(const float4*)(b1p + kbase + 4);

        // fc1 for this thread's 8 k-values, both m-tiles -> A-fragments
        float a0[8], a1[8];
        a0[0] = fmaxf(0.f, fmaf(xv0, w0.x, c0.x)); a1[0] = fmaxf(0.f, fmaf(xv1, w0.x, c0.x));
        a0[1] = fmaxf(0.f, fmaf(xv0, w0.y, c0.y)); a1[1] = fmaxf(0.f, fmaf(xv1, w0.y, c0.y));
        a0[2] = fmaxf(0.f, fmaf(xv0, w0.z, c0.z)); a1[2] = fmaxf(0.f, fmaf(xv1, w0.z, c0.z));
        a0[3] = fmaxf(0.f, fmaf(xv0, w0.w, c0.w)); a1[3] = fmaxf(0.f, fmaf(xv1, w0.w, c0.w));
        a0[4] = fmaxf(0.f, fmaf(xv0, w1.x, c1.x)); a1[4] = fmaxf(0.f, fmaf(xv1, w1.x, c1.x));
        a0[5] = fmaxf(0.f, fmaf(xv0, w1.y, c1.y)); a1[5] = fmaxf(0.f, fmaf(xv1, w1.y, c1.y));
        a0[6] = fmaxf(0.f, fmaf(xv0, w1.z, c1.z)); a1[6] = fmaxf(0.f, fmaf(xv1, w1.z, c1.z));
        a0[7] = fmaxf(0.f, fmaf(xv0, w1.w, c1.w)); a1[7] = fmaxf(0.f, fmaf(xv1, w1.w, c1.w));

        short8 af0, af1;
        unsigned* u0 = (unsigned*)&af0;
        unsigned* u1 = (unsigned*)&af1;
#pragma unroll
        for (int p = 0; p < 4; ++p) {
            u0[p] = pack_bf16_rhu(a0[2 * p], a0[2 * p + 1]);
            u1[p] = pack_bf16_rhu(a1[2 * p], a1[2 * p + 1]);
        }

#pragma unroll
        for (int nt = 0; nt < 4; ++nt) {
            const short8 bf = *(const short8*)(w2b + ((kk * 4 + nt) * 64) * 8);
            acc[0][nt] = __builtin_amdgcn_mfma_f32_16x16x32_bf16(af0, bf, acc[0][nt], 0, 0, 0);
            acc[1][nt] = __builtin_amdgcn_mfma_f32_16x16x32_bf16(af1, bf, acc[1][nt], 0, 0, 0);
        }
    }

    // ---- epilogue: h2 = relu(acc + b2); contrib = h2 . w3; reduce over o ----
    const float* b2p = ws + OFF_B2P + f * NP;
    const float* w3p = ws + OFF_W3P + f * NP;

    float rp[2][4] = {{0.f, 0.f, 0.f, 0.f}, {0.f, 0.f, 0.f, 0.f}};
#pragma unroll
    for (int nt = 0; nt < 4; ++nt) {
        const float bo = b2p[nt * 16 + ln];
        const float wo = w3p[nt * 16 + ln];
#pragma unroll
        for (int mt = 0; mt < 2; ++mt)
#pragma unroll
            for (int r = 0; r < 4; ++r)
                rp[mt][r] = fmaf(fmaxf(acc[mt][nt][r] + bo, 0.f), wo, rp[mt][r]);
    }
#pragma unroll
    for (int mt = 0; mt < 2; ++mt)
#pragma unroll
        for (int r = 0; r < 4; ++r) {
            float v = rp[mt][r];
            v += __shfl_xor(v, 1);
            v += __shfl_xor(v, 2);
            v += __shfl_xor(v, 4);
            v += __shfl_xor(v, 8);
            if (ln == 0)
                atomicAdd(out + b0 + mt * 16 + qd * 4 + r, v);  // C row = qd*4+r
        }
}

__global__ __launch_bounds__(256) void nam_finish(
    float* __restrict__ out, const float* __restrict__ bias)
{
    const int b = blockIdx.x * blockDim.x + threadIdx.x;
    out[b] = 1.0f / (1.0f + expf(-(out[b] + bias[0])));
}

extern "C" void kernel_launch(void* const* d_in, const int* in_sizes, int n_in,
                              void* d_out, int out_size, void* d_ws, size_t ws_size,
                              hipStream_t stream) {
    const float* x    = (const float*)d_in[0];
    const float* W1   = (const float*)d_in[1];
    const float* b1   = (const float*)d_in[2];
    const float* W2   = (const float*)d_in[3];
    const float* b2   = (const float*)d_in[4];
    const float* W3   = (const float*)d_in[5];
    const float* bias = (const float*)d_in[6];
    float* out = (float*)d_out;
    float* ws  = (float*)d_ws;   // ~12.4 MB used

    hipMemsetAsync(out, 0, (size_t)BATCH * sizeof(float), stream);

    prep_weights<<<NFEAT, 256, 0, stream>>>(W1, b1, W2, b2, W3, ws);
    transpose_x<<<dim3(BATCH / 64, NFEAT / 64), 256, 0, stream>>>(x, ws + OFF_XT);

    nam_mfma<<<dim3(BATCH / 32, NFEAT / 4), 256, 0, stream>>>(ws, out);

    nam_finish<<<BATCH / 256, 256, 0, stream>>>(out, bias);
}

// Round 6
// 162.595 us; speedup vs baseline: 5.0128x; 1.0202x over previous
//
#include <hip/hip_runtime.h>
#include <math.h>

// Problem constants
#define BATCH 8192
#define NFEAT 256
#define NH1   100     // fc1 width (K of fc2)
#define NH2   50      // fc2 width (N of fc2)
#define KP    128     // K padded: 4 MFMA k-steps of 32
#define NP    64      // N padded: 4 n-tiles of 16

typedef __attribute__((ext_vector_type(8))) _Float16 half8;   // 8 f16 (4 VGPRs)
typedef __attribute__((ext_vector_type(2))) __fp16   fp16x2;  // cvt_pkrtz result type
typedef __attribute__((ext_vector_type(4))) float float4v;    // MFMA acc

// ---- workspace layout ----
// w2h : NFEAT*4*4*64*8 f16  = 4 MB  (fragment-ordered, zero-padded)
// w1p : NFEAT*KP fp32       = 128 KB (zero-padded)
// b1p : NFEAT*KP fp32       = 128 KB
// b2p : NFEAT*NP fp32       = 64 KB
// w3p : NFEAT*NP fp32       = 64 KB
// xT  : NFEAT*BATCH fp32    = 8 MB
#define W2H_ELEMS  (NFEAT * 4 * 4 * 64 * 8)
#define OFF_W1P    (W2H_ELEMS / 2)            // fp32 units from ws start
#define OFF_B1P    (OFF_W1P + NFEAT * KP)
#define OFF_B2P    (OFF_B1P + NFEAT * KP)
#define OFF_W3P    (OFF_B2P + NFEAT * NP)
#define OFF_XT     (OFF_W3P + NFEAT * NP)

// ---- fused pre-pass ----
// blocks [0, NFEAT): pad+convert weights for feature f=blockIdx.x.
//   w2h[f][kk][nt][lane][j] = f16(W2[f][o=16*nt+(lane&15)][h=32*kk+8*(lane>>4)+j])
// blocks [NFEAT, NFEAT + 128*4): 64x64 transpose tile of x -> xT.
__global__ __launch_bounds__(256) void prep(
    const float* __restrict__ x,
    const float* __restrict__ W1, const float* __restrict__ b1,
    const float* __restrict__ W2, const float* __restrict__ b2,
    const float* __restrict__ W3, float* __restrict__ ws)
{
    __shared__ float tile[64][65];
    const int bx = blockIdx.x;
    const int t  = threadIdx.x;

    if (bx < NFEAT) {
        const int f = bx;
        float* w1p = ws + OFF_W1P + f * KP;
        float* b1p = ws + OFF_B1P + f * KP;
        float* b2p = ws + OFF_B2P + f * NP;
        float* w3p = ws + OFF_W3P + f * NP;
        _Float16* w2h = (_Float16*)ws + (size_t)f * (4 * 4 * 64 * 8);

        if (t < KP) {
            w1p[t] = (t < NH1) ? W1[f * NH1 + t] : 0.f;
            b1p[t] = (t < NH1) ? b1[f * NH1 + t] : 0.f;
        }
        if (t < NP)          b2p[t]      = (t < NH2)      ? b2[f * NH2 + t] : 0.f;
        else if (t < 2 * NP) w3p[t - NP] = (t - NP < NH2) ? W3[f * NH2 + (t - NP)] : 0.f;

        const float* w2g = W2 + (size_t)f * NH2 * NH1;
#pragma unroll
        for (int i = 0; i < 32; ++i) {
            const int e    = i * 256 + t;        // 0..8191
            const int j    = e & 7;
            const int lane = (e >> 3) & 63;
            const int nt   = (e >> 9) & 3;
            const int kk   = e >> 11;
            const int o    = nt * 16 + (lane & 15);
            const int h    = kk * 32 + (lane >> 4) * 8 + j;
            const float v  = (o < NH2 && h < NH1) ? w2g[o * NH1 + h] : 0.f;
            w2h[e] = (_Float16)v;
        }
    } else {
        const int i  = bx - NFEAT;
        const int b0 = (i & 127) * 64;
        const int f0 = (i >> 7) * 64;
        float* xT = ws + OFF_XT;
        const int c = t & 63, r0 = t >> 6;
#pragma unroll
        for (int k = 0; k < 16; ++k)
            tile[r0 + k * 4][c] = x[(size_t)(b0 + r0 + k * 4) * NFEAT + f0 + c];
        __syncthreads();
#pragma unroll
        for (int k = 0; k < 16; ++k)
            xT[(size_t)(f0 + r0 + k * 4) * BATCH + b0 + c] = tile[c][r0 + k * 4];
    }
}

// ---- main: one wave = (64 batch rows, one feature). No LDS, no barriers.
// fc1 computed directly into fp16 A-fragments (cvt_pkrtz); all 16 B-fragments
// prefetched into registers up front (L2 traffic halved vs 2-mt version).
__global__ __launch_bounds__(256, 2) void nam_mfma(
    const float* __restrict__ ws,
    float* __restrict__ out)
{
    const int t  = threadIdx.x;
    const int wv = t >> 6;
    const int ln = t & 15;
    const int qd = (t >> 4) & 3;
    const int f  = blockIdx.y * 4 + wv;
    const int b0 = blockIdx.x * 64;

    const float* xTp = ws + OFF_XT + (size_t)f * BATCH + b0;
    const float* w1p = ws + OFF_W1P + f * KP;
    const float* b1p = ws + OFF_B1P + f * KP;
    const _Float16* w2h =
        (const _Float16*)ws + (size_t)f * (4 * 4 * 64 * 8) + (t & 63) * 8;

    float xv[4];
#pragma unroll
    for (int mt = 0; mt < 4; ++mt) xv[mt] = xTp[mt * 16 + ln];

    // Prefetch all B-fragments: 16 x 1KB coalesced loads, 64 VGPRs.
    half8 bf[4][4];
#pragma unroll
    for (int kk = 0; kk < 4; ++kk)
#pragma unroll
        for (int nt = 0; nt < 4; ++nt)
            bf[kk][nt] = *(const half8*)(w2h + (kk * 4 + nt) * 512);

    float4v acc[4][4];
#pragma unroll
    for (int mt = 0; mt < 4; ++mt)
#pragma unroll
        for (int nt = 0; nt < 4; ++nt) acc[mt][nt] = (float4v){0.f, 0.f, 0.f, 0.f};

#pragma unroll
    for (int kk = 0; kk < 4; ++kk) {
        const int kbase = kk * 32 + qd * 8;
        const float4 w0 = *(const float4*)(w1p + kbase);
        const float4 w1 = *(const float4*)(w1p + kbase + 4);
        const float4 c0 = *(const float4*)(b1p + kbase);
        const float4 c1 = *(const float4*)(b1p + kbase + 4);

#pragma unroll
        for (int mt = 0; mt < 4; ++mt) {
            const float xm = xv[mt];
            float a[8];
            a[0] = fmaxf(0.f, fmaf(xm, w0.x, c0.x));
            a[1] = fmaxf(0.f, fmaf(xm, w0.y, c0.y));
            a[2] = fmaxf(0.f, fmaf(xm, w0.z, c0.z));
            a[3] = fmaxf(0.f, fmaf(xm, w0.w, c0.w));
            a[4] = fmaxf(0.f, fmaf(xm, w1.x, c1.x));
            a[5] = fmaxf(0.f, fmaf(xm, w1.y, c1.y));
            a[6] = fmaxf(0.f, fmaf(xm, w1.z, c1.z));
            a[7] = fmaxf(0.f, fmaf(xm, w1.w, c1.w));

            half8 af;
            fp16x2* ap = (fp16x2*)&af;
            ap[0] = __builtin_amdgcn_cvt_pkrtz(a[0], a[1]);
            ap[1] = __builtin_amdgcn_cvt_pkrtz(a[2], a[3]);
            ap[2] = __builtin_amdgcn_cvt_pkrtz(a[4], a[5]);
            ap[3] = __builtin_amdgcn_cvt_pkrtz(a[6], a[7]);

#pragma unroll
            for (int nt = 0; nt < 4; ++nt)
                acc[mt][nt] = __builtin_amdgcn_mfma_f32_16x16x32_f16(
                    af, bf[kk][nt], acc[mt][nt], 0, 0, 0);
        }
    }

    // ---- epilogue: h2 = relu(acc + b2); contrib = h2 . w3; reduce over o ----
    const float* b2p = ws + OFF_B2P + f * NP;
    const float* w3p = ws + OFF_W3P + f * NP;

    float rp[4][4] = {{0.f}, {0.f}, {0.f}, {0.f}};
#pragma unroll
    for (int nt = 0; nt < 4; ++nt) {
        const float bo = b2p[nt * 16 + ln];
        const float wo = w3p[nt * 16 + ln];
#pragma unroll
        for (int mt = 0; mt < 4; ++mt)
#pragma unroll
            for (int r = 0; r < 4; ++r)
                rp[mt][r] = fmaf(fmaxf(acc[mt][nt][r] + bo, 0.f), wo, rp[mt][r]);
    }
#pragma unroll
    for (int mt = 0; mt < 4; ++mt)
#pragma unroll
        for (int r = 0; r < 4; ++r) {
            float v = rp[mt][r];
            v += __shfl_xor(v, 1);
            v += __shfl_xor(v, 2);
            v += __shfl_xor(v, 4);
            v += __shfl_xor(v, 8);
            if (ln == 0)
                atomicAdd(out + b0 + mt * 16 + qd * 4 + r, v);  // C row = qd*4+r
        }
}

__global__ __launch_bounds__(256) void nam_finish(
    float* __restrict__ out, const float* __restrict__ bias)
{
    const int b = blockIdx.x * blockDim.x + threadIdx.x;
    out[b] = 1.0f / (1.0f + expf(-(out[b] + bias[0])));
}

extern "C" void kernel_launch(void* const* d_in, const int* in_sizes, int n_in,
                              void* d_out, int out_size, void* d_ws, size_t ws_size,
                              hipStream_t stream) {
    const float* x    = (const float*)d_in[0];
    const float* W1   = (const float*)d_in[1];
    const float* b1   = (const float*)d_in[2];
    const float* W2   = (const float*)d_in[3];
    const float* b2   = (const float*)d_in[4];
    const float* W3   = (const float*)d_in[5];
    const float* bias = (const float*)d_in[6];
    float* out = (float*)d_out;
    float* ws  = (float*)d_ws;   // ~12.4 MB used

    (void)hipMemsetAsync(out, 0, (size_t)BATCH * sizeof(float), stream);

    prep<<<NFEAT + (BATCH / 64) * (NFEAT / 64), 256, 0, stream>>>(
        x, W1, b1, W2, b2, W3, ws);

    nam_mfma<<<dim3(BATCH / 64, NFEAT / 4), 256, 0, stream>>>(ws, out);

    nam_finish<<<BATCH / 256, 256, 0, stream>>>(out, bias);
}